// Round 8
// baseline (300.401 us; speedup 1.0000x reference)
//
#include <hip/hip_runtime.h>

// GCN block: h1 = ReLU(Agg(x@W1)+b1); h2 = ReLU(Agg(h1@W2)+b2); out = BN(h2)
// R23: L2-resident slice gathers done RIGHT. 4 feature-slices of 64B/row
// (3.2MB < 4MB/XCD L2); each slice phase is a SEPARATE LAUNCH (whole GPU on
// one slice -> true residency; R22's in-kernel phases drifted). Node per
// 16-lane group; row = one 64B line; 16 dword-gathers (incl self slot) per
// node per phase with ONE vmcnt(0); cross-node slot prefetch restored (all
// normal loads before the wait, consumed after - R18/R20 discipline; R22
// dropped this and serialized slot->gather). NT stores only (don't evict
// slice); bucket loads normal (1 line/node). Tail deg>=16: clamped 8-chunks.

#define D 128
#define CAP 96   // max in-degree capacity

typedef __attribute__((ext_vector_type(8))) short bf16x8;
typedef __attribute__((ext_vector_type(4))) float f32x4;
typedef __attribute__((ext_vector_type(4))) int i32x4;

__device__ inline float2 bf2x2(unsigned u) {
    float2 r;
    r.x = __uint_as_float(u << 16);
    r.y = __uint_as_float(u & 0xffff0000u);
    return r;
}
__device__ inline unsigned short f2bf(float f) {
    unsigned u = __float_as_uint(f);
    u += 0x7fffu + ((u >> 16) & 1u);   // round-to-nearest-even
    return (unsigned short)(u >> 16);
}
__device__ inline unsigned pack2(float a, float b) {
    return (unsigned)f2bf(a) | ((unsigned)f2bf(b) << 16);
}

// ------- fused histogram+fill (sequential slots) + W transpose + zero rows -----
__global__ void k_histfill(const int* __restrict__ row, const int* __restrict__ col,
                           int* __restrict__ cnt, int* __restrict__ bucket, int E,
                           const float* __restrict__ W1, const float* __restrict__ W2,
                           unsigned short* __restrict__ Wt1,
                           unsigned short* __restrict__ Wt2,
                           unsigned* __restrict__ hsb_u, unsigned* __restrict__ g2b_u,
                           int N) {
    int e = blockIdx.x * blockDim.x + threadIdx.x;
    if (e < E) {
        int c = col[e];
        int slot = atomicAdd(&cnt[c], 1);
        if (slot < CAP) bucket[(size_t)c * CAP + slot] = row[e];
    }
    if (blockIdx.x < D) {
        int k = blockIdx.x;
        int t = threadIdx.x;
        if (t < D) Wt1[t * D + k] = f2bf(W1[k * D + t]);
        else       Wt2[(t - D) * D + k] = f2bf(W2[k * D + (t - D)]);
    } else if (blockIdx.x == D && threadIdx.x < 128) {
        // zero the sentinel row (row N) of each of the 4 slices of hsb and g2b
        int t = threadIdx.x;
        int which = t >> 4, idx = t & 15;
        size_t selem_u = (size_t)(N + 1) * 16;   // uints per slice
        unsigned* bp = (which < 4 ? hsb_u : g2b_u)
                       + (size_t)(which & 3) * selem_u + (size_t)N * 16;
        bp[idx] = 0u;
    }
}

// ------ 16-wave GEMM compute; epilogue writes QUARTERED prescaled slices ------
__device__ inline void gemm_compute16(const unsigned short* Xs, const unsigned short* Ws,
                                      const int* __restrict__ cnt,
                                      unsigned short* __restrict__ out, size_t selem,
                                      int n, int row0) {
    int tid = threadIdx.x;
    int w = tid >> 6;          // 0..15
    int wm = w >> 1;           // m-tile 0..7
    int wn = w & 1;            // n-half 0..1
    int lane = tid & 63;
    int m16 = lane & 15;
    int quad = lane >> 4;

    f32x4 acc[4];
#pragma unroll
    for (int u = 0; u < 4; u++) acc[u] = (f32x4){0.f, 0.f, 0.f, 0.f};

#pragma unroll
    for (int kc = 0; kc < 4; kc++) {
        bf16x8 a = *(const bf16x8*)&Xs[(wm * 16 + m16) * 136 + kc * 32 + quad * 8];
        bf16x8 b[4];
#pragma unroll
        for (int u = 0; u < 4; u++)
            b[u] = *(const bf16x8*)&Ws[((wn * 4 + u) * 16 + m16) * 136 + kc * 32 + quad * 8];
#pragma unroll
        for (int u = 0; u < 4; u++)
            acc[u] = __builtin_amdgcn_mfma_f32_16x16x32_bf16(a, b[u], acc[u], 0, 0, 0);
    }

    int rbase = row0 + wm * 16 + quad * 4;
#pragma unroll
    for (int i = 0; i < 4; i++) {
        int r = rbase + i;
        if (r < n) {
            float sc = rsqrtf((float)cnt[r] + 1.0f);
#pragma unroll
            for (int u = 0; u < 4; u++) {
                int f = (wn * 4 + u) * 16 + m16;
                int q = f >> 5, fo = f & 31;
                out[(size_t)q * selem + (size_t)r * 32 + fo] = f2bf(acc[u][i] * sc);
            }
        }
    }
}

// -- GEMM1: quartered prescaled hsb; pads bucket: self at L, 31 sentinels --
__global__ __launch_bounds__(1024) void k_gemm1(
        const float* __restrict__ Xf, const unsigned short* __restrict__ Wt,
        const int* __restrict__ cnt, int* __restrict__ bucket,
        unsigned short* __restrict__ out, size_t selem, int n) {
    __shared__ unsigned short Xs[128 * 136];
    __shared__ unsigned short Ws[128 * 136];
    int tid = threadIdx.x;
    int row0 = blockIdx.x * 128;

#pragma unroll
    for (int i = 0; i < 2; i++) {
        int c = tid + 1024 * i;
        int r = c >> 4;
        int kc = (c & 15) * 8;
        float4 va = {0.f, 0.f, 0.f, 0.f}, vb = {0.f, 0.f, 0.f, 0.f};
        if (row0 + r < n) {
            va = *(const float4*)&Xf[(size_t)(row0 + r) * D + kc];
            vb = *(const float4*)&Xf[(size_t)(row0 + r) * D + kc + 4];
        }
        ushort4 o0, o1;
        o0.x = f2bf(va.x); o0.y = f2bf(va.y); o0.z = f2bf(va.z); o0.w = f2bf(va.w);
        o1.x = f2bf(vb.x); o1.y = f2bf(vb.y); o1.z = f2bf(vb.z); o1.w = f2bf(vb.w);
        *(ushort4*)&Xs[r * 136 + kc] = o0;
        *(ushort4*)&Xs[r * 136 + kc + 4] = o1;
    }
#pragma unroll
    for (int i = 0; i < 2; i++) {
        int c = tid + 1024 * i;
        int r = c >> 4;
        int kc = (c & 15) * 8;
        uint4 v = *(const uint4*)&Wt[r * D + kc];
        *(uint4*)&Ws[r * 136 + kc] = v;
    }
    // bucket pad: 8 threads per node; self at L, sentinels L+1..L+31 (<CAP)
    {
        int nl = tid >> 3;
        int node = row0 + nl;
        if (node < n) {
            int L = min(cnt[node], CAP - 1);
            int* bp = bucket + (size_t)node * CAP;
            if ((tid & 7) == 0) bp[L] = node;           // self slot
#pragma unroll
            for (int i = (tid & 7); i < 31; i += 8) {
                int p = L + 1 + i;
                if (p < CAP) bp[p] = n;                  // sentinel -> zero row
            }
        }
    }
    __syncthreads();
    gemm_compute16(Xs, Ws, cnt, out, selem, n, row0);
}

// -------- GEMM2: bf16 input a1b -> quartered prescaled g2b --------
__global__ __launch_bounds__(1024) void k_gemm2(
        const unsigned short* __restrict__ A, const unsigned short* __restrict__ Wt,
        const int* __restrict__ cnt, unsigned short* __restrict__ out,
        size_t selem, int n) {
    __shared__ unsigned short Xs[128 * 136];
    __shared__ unsigned short Ws[128 * 136];
    int tid = threadIdx.x;
    int row0 = blockIdx.x * 128;
#pragma unroll
    for (int i = 0; i < 2; i++) {
        int c = tid + 1024 * i;
        int r = c >> 4;
        int kc = (c & 15) * 8;
        uint4 v = {0u, 0u, 0u, 0u};
        if (row0 + r < n) v = *(const uint4*)&A[(size_t)(row0 + r) * D + kc];
        *(uint4*)&Xs[r * 136 + kc] = v;
    }
#pragma unroll
    for (int i = 0; i < 2; i++) {
        int c = tid + 1024 * i;
        int r = c >> 4;
        int kc = (c & 15) * 8;
        uint4 v = *(const uint4*)&Wt[r * D + kc];
        *(uint4*)&Ws[r * 136 + kc] = v;
    }
    __syncthreads();
    gemm_compute16(Xs, Ws, cnt, out, selem, n, row0);
}

// ---- forced-MLP gather: 8 concurrent dword gathers (issue only, no wait) ----
struct G8D { unsigned a, b, c, d, e, f, g, h; };

__device__ inline G8D issue8d(const char* base,
                              unsigned o0, unsigned o1, unsigned o2, unsigned o3,
                              unsigned o4, unsigned o5, unsigned o6, unsigned o7) {
    G8D r;
    asm volatile(
        "global_load_dword %0, %8, %16\n\t"
        "global_load_dword %1, %9, %16\n\t"
        "global_load_dword %2, %10, %16\n\t"
        "global_load_dword %3, %11, %16\n\t"
        "global_load_dword %4, %12, %16\n\t"
        "global_load_dword %5, %13, %16\n\t"
        "global_load_dword %6, %14, %16\n\t"
        "global_load_dword %7, %15, %16"
        : "=&v"(r.a), "=&v"(r.b), "=&v"(r.c), "=&v"(r.d),
          "=&v"(r.e), "=&v"(r.f), "=&v"(r.g), "=&v"(r.h)
        : "v"(o0), "v"(o1), "v"(o2), "v"(o3),
          "v"(o4), "v"(o5), "v"(o6), "v"(o7),
          "s"(base));
    return r;
}

__device__ inline void wait_vm0() {
    asm volatile("s_waitcnt vmcnt(0)" ::: "memory");
    __builtin_amdgcn_sched_barrier(0);   // keep consumers below the wait
}

__device__ inline void cons8(const G8D& g, float& A0, float& A1) {
    float2 x;
    x = bf2x2(g.a); A0 += x.x; A1 += x.y;
    x = bf2x2(g.b); A0 += x.x; A1 += x.y;
    x = bf2x2(g.c); A0 += x.x; A1 += x.y;
    x = bf2x2(g.d); A0 += x.x; A1 += x.y;
    x = bf2x2(g.e); A0 += x.x; A1 += x.y;
    x = bf2x2(g.f); A0 += x.x; A1 += x.y;
    x = bf2x2(g.g); A0 += x.x; A1 += x.y;
    x = bf2x2(g.h); A0 += x.x; A1 += x.y;
}

#define QOFF(s) ((((unsigned)(s)) << 6) + l4b)

// ---- per-node slice aggregation body (16 slots incl self, one wait; tail) ----
// Returns A0,A1 = sums of this lane's 2 features over all T edges of `node`.
__device__ inline void agg_node_slice(const char* sq, const int* bp,
                                      i32x4 sa, i32x4 sb, i32x4 sc, i32x4 sd,
                                      int dc, int N, unsigned l4b,
                                      const i32x4* nb4, int nn,
                                      i32x4& na, i32x4& nbv, i32x4& ncv, i32x4& nd,
                                      int& ndc, const int* __restrict__ cnt,
                                      float& A0, float& A1) {
    G8D g0 = issue8d(sq, QOFF(sa[0]), QOFF(sa[1]), QOFF(sa[2]), QOFF(sa[3]),
                         QOFF(sb[0]), QOFF(sb[1]), QOFF(sb[2]), QOFF(sb[3]));
    G8D g1 = issue8d(sq, QOFF(sc[0]), QOFF(sc[1]), QOFF(sc[2]), QOFF(sc[3]),
                         QOFF(sd[0]), QOFF(sd[1]), QOFF(sd[2]), QOFF(sd[3]));
    // prefetch next node's 16 slots (one 64B line) + cnt, before the wait
    na = nb4[0]; nbv = nb4[1]; ncv = nb4[2]; nd = nb4[3];
    ndc = cnt[nn];
    wait_vm0();
    A0 = 0.f; A1 = 0.f;
    cons8(g0, A0, A1);
    cons8(g1, A0, A1);
    int T = min(dc, CAP - 1) + 1;    // edges incl self; slots [T,16) = sentinel
    if (__builtin_expect(__any(T > 16), 0)) {
#pragma unroll 1
        for (int k = 16; __any(T > k); k += 8) {
            i32x4 xa = *(const i32x4*)(bp + k);
            i32x4 xb = *(const i32x4*)(bp + k + 4);
            // clamp: beyond this group's defined region -> sentinel row N
            unsigned s0 = (k + 0 < T) ? xa[0] : N;
            unsigned s1 = (k + 1 < T) ? xa[1] : N;
            unsigned s2 = (k + 2 < T) ? xa[2] : N;
            unsigned s3 = (k + 3 < T) ? xa[3] : N;
            unsigned s4 = (k + 4 < T) ? xb[0] : N;
            unsigned s5 = (k + 5 < T) ? xb[1] : N;
            unsigned s6 = (k + 6 < T) ? xb[2] : N;
            unsigned s7 = (k + 7 < T) ? xb[3] : N;
            G8D t = issue8d(sq, QOFF(s0), QOFF(s1), QOFF(s2), QOFF(s3),
                                QOFF(s4), QOFF(s5), QOFF(s6), QOFF(s7));
            wait_vm0();
            cons8(t, A0, A1);
        }
    }
}

// ---------------- agg1 phase q: slice gather -> a1b (std layout) ----------------
__global__ __launch_bounds__(1024) void k_agg1p(
        const char* __restrict__ sq, const int* __restrict__ bucket,
        const int* __restrict__ cnt, const float* __restrict__ bias,
        unsigned short* __restrict__ outp, int q, int N) {
    int tid = threadIdx.x;
    int l16 = tid & 15;
    unsigned l4b = (unsigned)l16 * 4u;
    int wgrp = tid >> 4;               // 0..63: node-group in block
    int stride = gridDim.x * 64;
    int node = blockIdx.x * 64 + wgrp;

    float2 bq = *(const float2*)&bias[q * 32 + l16 * 2];

    int nc = min(node, N - 1);
    const int* bp = bucket + (size_t)nc * CAP;
    i32x4 sa = ((const i32x4*)bp)[0], sb = ((const i32x4*)bp)[1];
    i32x4 sc = ((const i32x4*)bp)[2], sd = ((const i32x4*)bp)[3];
    int dc = cnt[nc];
#pragma unroll 1
    for (; node < N; node += stride) {
        int nn = min(node + stride, N - 1);
        const int* bpn = bucket + (size_t)nn * CAP;
        i32x4 na, nbv, ncv, nd;
        int ndc;
        float A0, A1;
        agg_node_slice(sq, bp, sa, sb, sc, sd, dc, N, l4b,
                       (const i32x4*)bpn, nn, na, nbv, ncv, nd, ndc, cnt, A0, A1);
        float dn = rsqrtf((float)dc + 1.0f);
        unsigned o = pack2(fmaxf(dn * A0 + bq.x, 0.f),
                           fmaxf(dn * A1 + bq.y, 0.f));
        __builtin_nontemporal_store(
            o, (unsigned*)&outp[(size_t)node * D + q * 32 + l16 * 2]);
        bp = bpn; sa = na; sb = nbv; sc = ncv; sd = nd; dc = ndc;
    }
}

// ------- agg2 phase q: slice gather + BN partial stats -> h2b, S -------
__global__ __launch_bounds__(1024) void k_agg2p(
        const char* __restrict__ sq, const int* __restrict__ bucket,
        const int* __restrict__ cnt, const float* __restrict__ bias,
        unsigned short* __restrict__ h2, float* __restrict__ S, int q, int N) {
    int tid = threadIdx.x;
    int l16 = tid & 15;
    unsigned l4b = (unsigned)l16 * 4u;
    int wgrp = tid >> 4;
    int stride = gridDim.x * 64;
    int node = blockIdx.x * 64 + wgrp;

    float2 bq = *(const float2*)&bias[q * 32 + l16 * 2];
    float st0 = 0.f, st1 = 0.f, sq0 = 0.f, sq1 = 0.f;

    int nc = min(node, N - 1);
    const int* bp = bucket + (size_t)nc * CAP;
    i32x4 sa = ((const i32x4*)bp)[0], sb = ((const i32x4*)bp)[1];
    i32x4 sc = ((const i32x4*)bp)[2], sd = ((const i32x4*)bp)[3];
    int dc = cnt[nc];
#pragma unroll 1
    for (; node < N; node += stride) {
        int nn = min(node + stride, N - 1);
        const int* bpn = bucket + (size_t)nn * CAP;
        i32x4 na, nbv, ncv, nd;
        int ndc;
        float A0, A1;
        agg_node_slice(sq, bp, sa, sb, sc, sd, dc, N, l4b,
                       (const i32x4*)bpn, nn, na, nbv, ncv, nd, ndc, cnt, A0, A1);
        float dn = rsqrtf((float)dc + 1.0f);
        float v0 = fmaxf(dn * A0 + bq.x, 0.f);
        float v1 = fmaxf(dn * A1 + bq.y, 0.f);
        __builtin_nontemporal_store(
            pack2(v0, v1), (unsigned*)&h2[(size_t)node * D + q * 32 + l16 * 2]);
        st0 += v0; st1 += v1; sq0 += v0 * v0; sq1 += v1 * v1;
        bp = bpn; sa = na; sb = nbv; sc = ncv; sd = nd; dc = ndc;
    }

    // reduce across the 4 groups of each wave (lane bits 4,5)
    st0 += __shfl_xor(st0, 16); st0 += __shfl_xor(st0, 32);
    st1 += __shfl_xor(st1, 16); st1 += __shfl_xor(st1, 32);
    sq0 += __shfl_xor(sq0, 16); sq0 += __shfl_xor(sq0, 32);
    sq1 += __shfl_xor(sq1, 16); sq1 += __shfl_xor(sq1, 32);

    __shared__ float sm[16][16][4];
    int wv = tid >> 6;
    if (((tid >> 4) & 3) == 0) {
        sm[wv][l16][0] = st0; sm[wv][l16][1] = st1;
        sm[wv][l16][2] = sq0; sm[wv][l16][3] = sq1;
    }
    __syncthreads();
    if (tid < 32) {
        int f = tid, li = f >> 1, hi = f & 1;
        float s = 0.f, t2 = 0.f;
#pragma unroll
        for (int ww = 0; ww < 16; ww++) {
            s += sm[ww][li][hi];
            t2 += sm[ww][li][2 + hi];
        }
        atomicAdd(&S[(q * 32 + f) * 16], s);
        atomicAdd(&S[4096 + (q * 32 + f) * 16], t2);
    }
}

// ---------------- BN normalize: bf16 h2 -> f32 out ----------------
__global__ void k_bn(const unsigned* __restrict__ z2, const float* __restrict__ S,
                     const float* __restrict__ gamma, const float* __restrict__ beta,
                     float* __restrict__ out, int N) {
    int i = blockIdx.x * blockDim.x + threadIdx.x;   // uint4 index (8 features)
    int total = N * (D / 8);
    if (i >= total) return;
    int c8 = (i & (D / 8 - 1)) * 8;
    uint4 u = *(const uint4*)&z2[(size_t)i * 4];
    float v[8];
    float2 t;
    t = bf2x2(u.x); v[0] = t.x; v[1] = t.y;
    t = bf2x2(u.y); v[2] = t.x; v[3] = t.y;
    t = bf2x2(u.z); v[4] = t.x; v[5] = t.y;
    t = bf2x2(u.w); v[6] = t.x; v[7] = t.y;
    float invN = 1.0f / (float)N;
    float4 o0, o1;
#pragma unroll
    for (int j = 0; j < 8; j++) {
        float s = S[(c8 + j) * 16];
        float s2 = S[4096 + (c8 + j) * 16];
        float mu = s * invN;
        float iv = rsqrtf(fmaxf(s2 * invN - mu * mu, 0.f) + 1e-5f);
        float val = gamma[c8 + j] * (v[j] - mu) * iv + beta[c8 + j];
        if (j < 4) (&o0.x)[j] = val; else (&o1.x)[j - 4] = val;
    }
    size_t base = (size_t)i * 8;
    *(float4*)&out[base] = o0;
    *(float4*)&out[base + 4] = o1;
}

static inline size_t align_up(size_t x) { return (x + 1023) & ~(size_t)1023; }

extern "C" void kernel_launch(void* const* d_in, const int* in_sizes, int n_in,
                              void* d_out, int out_size, void* d_ws, size_t ws_size,
                              hipStream_t stream) {
    const float* x     = (const float*)d_in[0];
    const int*   ei    = (const int*)d_in[1];
    const float* W1    = (const float*)d_in[2];
    const float* b1    = (const float*)d_in[3];
    const float* W2    = (const float*)d_in[4];
    const float* b2    = (const float*)d_in[5];
    const float* gamma = (const float*)d_in[6];
    const float* beta  = (const float*)d_in[7];

    int N = in_sizes[0] / D;
    int E = in_sizes[1] / 2;
    const int* row = ei;
    const int* col = ei + E;

    size_t selem = (size_t)(N + 1) * 32;     // ushorts per feature-quarter slice
    size_t sliceB = selem * 2;               // bytes per slice

    char* p = (char*)d_ws;
    int* cnt    = (int*)p;                   // cnt[N] ++ S[8192]: one memset
    float* S    = (float*)(cnt + N);
    p += align_up((size_t)(N + 8192) * 4);
    int* bucket = (int*)p;   p += align_up((size_t)N * CAP * 4);
    unsigned short* hsb = (unsigned short*)p; p += align_up((size_t)(N + 1) * D * 2);
    unsigned short* g2b = (unsigned short*)p; p += align_up((size_t)(N + 1) * D * 2);
    unsigned short* a1b = (unsigned short*)p; p += align_up((size_t)N * D * 2);
    unsigned short* h2b = (unsigned short*)p; p += align_up((size_t)N * D * 2);
    unsigned short* Wt1 = (unsigned short*)p; p += align_up((size_t)D * D * 2);
    unsigned short* Wt2 = (unsigned short*)p; p += align_up((size_t)D * D * 2);

    int gemmBlocks = (N + 127) / 128;        // 391
    int fillBlocks = (E + 255) / 256;        // 2344
    int aggBlocks  = 512;                    // 64 nodes/block-sweep, grid-stride

    hipMemsetAsync(cnt, 0, (size_t)(N + 8192) * 4, stream);
    k_histfill<<<fillBlocks, 256, 0, stream>>>(row, col, cnt, bucket, E,
                                               W1, W2, Wt1, Wt2,
                                               (unsigned*)hsb, (unsigned*)g2b, N);
    // layer 1 GEMM -> sliced prescaled hsb (+ bucket self/sentinel pad)
    k_gemm1<<<gemmBlocks, 1024, 0, stream>>>(x, Wt1, cnt, bucket, hsb, selem, N);
    // layer 1 aggregation: 4 L2-resident slice phases (separate launches)
    for (int q = 0; q < 4; q++)
        k_agg1p<<<aggBlocks, 1024, 0, stream>>>((const char*)hsb + q * sliceB,
                                                bucket, cnt, b1, a1b, q, N);
    // layer 2 GEMM -> sliced prescaled g2b
    k_gemm2<<<gemmBlocks, 1024, 0, stream>>>(a1b, Wt2, cnt, g2b, selem, N);
    // layer 2 aggregation + BN stats: 4 slice phases
    for (int q = 0; q < 4; q++)
        k_agg2p<<<aggBlocks, 1024, 0, stream>>>((const char*)g2b + q * sliceB,
                                                bucket, cnt, b2, h2b, S, q, N);
    // BN normalize
    k_bn<<<(N * (D / 8) + 255) / 256, 256, 0, stream>>>((const unsigned*)h2b, S,
                                                        gamma, beta, (float*)d_out, N);
}

// Round 10
// 229.932 us; speedup vs baseline: 1.3065x; 1.3065x over previous
//
#include <hip/hip_runtime.h>

// GCN block: h1 = ReLU(Agg(x@W1)+b1); h2 = ReLU(Agg(h1@W2)+b2); out = BN(h2)
// R24 (resubmit; R9 bench was an infra failure "container failed twice" —
// no kernel verdict). R20 baseline (233-237us verified) with ONE change:
// bucket slots as u16 (node ids < 65536) and CAP 96->48 (Poisson(12) max
// in-deg ~28). Bucket shrinks 19.2MB -> 4.8MB:
//  - k_histfill's 600k random write-allocates now target an L2-resident
//    4.8MB buffer (was ~77MB of fetch+writeback; modeled ~40us, never in
//    top-5 -> this round verifies),
//  - both agg passes read 4.8MB not 19.2MB of slots and stop polluting L2,
//    raising the gather-source hit rate (the established miss-throughput
//    wall: R15/R18/R21 all land 44-54us/pass regardless of chain shape).
// Same split-half slot order as R20 -> identical numerics.

#define D 128
#define CAP 48   // max in-degree capacity; Poisson(12) tail << 48

typedef __attribute__((ext_vector_type(8))) short bf16x8;
typedef __attribute__((ext_vector_type(4))) float f32x4;
typedef __attribute__((ext_vector_type(2))) unsigned u32x2;
typedef __attribute__((ext_vector_type(8))) unsigned short u16x8;

__device__ inline float2 bf2x2(unsigned u) {
    float2 r;
    r.x = __uint_as_float(u << 16);
    r.y = __uint_as_float(u & 0xffff0000u);
    return r;
}
__device__ inline unsigned short f2bf(float f) {
    unsigned u = __float_as_uint(f);
    u += 0x7fffu + ((u >> 16) & 1u);   // round-to-nearest-even
    return (unsigned short)(u >> 16);
}

// ------- fused histogram+fill: one atomic per edge; + W transpose-convert -------
// Split-half u16 bucket: slot s -> half s&1, index s>>1 (contiguous per half).
__global__ void k_histfill(const int* __restrict__ row, const int* __restrict__ col,
                           int* __restrict__ cnt, unsigned short* __restrict__ bucket,
                           int E,
                           const float* __restrict__ W1, const float* __restrict__ W2,
                           unsigned short* __restrict__ Wt1,
                           unsigned short* __restrict__ Wt2) {
    int e = blockIdx.x * blockDim.x + threadIdx.x;
    if (e < E) {
        int c = col[e];
        int slot = atomicAdd(&cnt[c], 1);
        if (slot < CAP)
            bucket[(size_t)c * CAP + (slot & 1) * (CAP / 2) + (slot >> 1)] =
                (unsigned short)row[e];
    }
    if (blockIdx.x < D) {
        int k = blockIdx.x;
        int t = threadIdx.x;
        if (t < D) Wt1[t * D + k] = f2bf(W1[k * D + t]);
        else       Wt2[(t - D) * D + k] = f2bf(W2[k * D + (t - D)]);
    }
}

// ------ 16-wave GEMM compute: wave w -> m-tile w>>1, n-half w&1 (4 n-tiles) ------
__device__ inline void gemm_compute16(const unsigned short* Xs, const unsigned short* Ws,
                                      const int* __restrict__ cnt,
                                      unsigned short* __restrict__ out, int n, int row0) {
    int tid = threadIdx.x;
    int w = tid >> 6;          // 0..15
    int wm = w >> 1;           // m-tile 0..7
    int wn = w & 1;            // n-half 0..1
    int lane = tid & 63;
    int m16 = lane & 15;
    int quad = lane >> 4;

    f32x4 acc[4];
#pragma unroll
    for (int u = 0; u < 4; u++) acc[u] = (f32x4){0.f, 0.f, 0.f, 0.f};

#pragma unroll
    for (int kc = 0; kc < 4; kc++) {
        bf16x8 a = *(const bf16x8*)&Xs[(wm * 16 + m16) * 136 + kc * 32 + quad * 8];
        bf16x8 b[4];
#pragma unroll
        for (int u = 0; u < 4; u++)
            b[u] = *(const bf16x8*)&Ws[((wn * 4 + u) * 16 + m16) * 136 + kc * 32 + quad * 8];
#pragma unroll
        for (int u = 0; u < 4; u++)
            acc[u] = __builtin_amdgcn_mfma_f32_16x16x32_bf16(a, b[u], acc[u], 0, 0, 0);
    }

    int rbase = row0 + wm * 16 + quad * 4;
#pragma unroll
    for (int i = 0; i < 4; i++) {
        int r = rbase + i;
        if (r < n) {
            float sc = rsqrtf((float)cnt[r] + 1.0f);
#pragma unroll
            for (int u = 0; u < 4; u++)
                out[(size_t)r * D + (wn * 4 + u) * 16 + m16] = f2bf(acc[u][i] * sc);
        }
    }
}

// -- GEMM1 (1024 thr, 16 waves): out[r] = bf16((X @ W)[r] * rsqrt(cnt[r]+1)) --
// Also sentinel-pads the bucket (slots [ch, ch+8) per node-half -> n).
__global__ __launch_bounds__(1024) void k_gemm1(
        const float* __restrict__ Xf, const unsigned short* __restrict__ Wt,
        const int* __restrict__ cnt, unsigned short* __restrict__ bucket,
        unsigned short* __restrict__ out, int n) {
    __shared__ unsigned short Xs[128 * 136];   // +8 pad: 2-way banks (free)
    __shared__ unsigned short Ws[128 * 136];
    int tid = threadIdx.x;
    int row0 = blockIdx.x * 128;

#pragma unroll
    for (int i = 0; i < 2; i++) {
        int c = tid + 1024 * i;
        int r = c >> 4;
        int kc = (c & 15) * 8;
        float4 va = {0.f, 0.f, 0.f, 0.f}, vb = {0.f, 0.f, 0.f, 0.f};
        if (row0 + r < n) {
            va = *(const float4*)&Xf[(size_t)(row0 + r) * D + kc];
            vb = *(const float4*)&Xf[(size_t)(row0 + r) * D + kc + 4];
        }
        ushort4 o0, o1;
        o0.x = f2bf(va.x); o0.y = f2bf(va.y); o0.z = f2bf(va.z); o0.w = f2bf(va.w);
        o1.x = f2bf(vb.x); o1.y = f2bf(vb.y); o1.z = f2bf(vb.z); o1.w = f2bf(vb.w);
        *(ushort4*)&Xs[r * 136 + kc] = o0;
        *(ushort4*)&Xs[r * 136 + kc + 4] = o1;
    }
#pragma unroll
    for (int i = 0; i < 2; i++) {
        int c = tid + 1024 * i;
        int r = c >> 4;
        int kc = (c & 15) * 8;
        uint4 v = *(const uint4*)&Wt[r * D + kc];
        *(uint4*)&Ws[r * 136 + kc] = v;
    }
    // sentinel pad: 8 threads per node, 2 writes each (one per half)
    {
        int nl = tid >> 3;
        int t8 = tid & 7;
        int node = row0 + nl;
        if (node < n) {
            int mm = min(cnt[node], CAP);
            unsigned short* bp = bucket + (size_t)node * CAP;
#pragma unroll
            for (int hf = 0; hf < 2; hf++) {
                int j = ((mm - hf + 1) >> 1) + t8;
                if (j < CAP / 2) bp[hf * (CAP / 2) + j] = (unsigned short)n;
            }
        }
    }
    __syncthreads();
    gemm_compute16(Xs, Ws, cnt, out, n, row0);
}

// ---- forced-MLP gather: 8 concurrent row gathers (issue only, no wait) ----
struct G8 { u32x2 a, b, c, d, e, f, g, h; };

__device__ inline G8 issue8(const uint2* __restrict__ hs2,
                            unsigned o0, unsigned o1, unsigned o2, unsigned o3,
                            unsigned o4, unsigned o5, unsigned o6, unsigned o7) {
    G8 r;
    asm volatile(
        "global_load_dwordx2 %0, %8, %16\n\t"
        "global_load_dwordx2 %1, %9, %16\n\t"
        "global_load_dwordx2 %2, %10, %16\n\t"
        "global_load_dwordx2 %3, %11, %16\n\t"
        "global_load_dwordx2 %4, %12, %16\n\t"
        "global_load_dwordx2 %5, %13, %16\n\t"
        "global_load_dwordx2 %6, %14, %16\n\t"
        "global_load_dwordx2 %7, %15, %16"
        : "=&v"(r.a), "=&v"(r.b), "=&v"(r.c), "=&v"(r.d),
          "=&v"(r.e), "=&v"(r.f), "=&v"(r.g), "=&v"(r.h)
        : "v"(o0), "v"(o1), "v"(o2), "v"(o3),
          "v"(o4), "v"(o5), "v"(o6), "v"(o7),
          "s"(hs2));
    return r;
}

__device__ inline void wait_vm0() {
    asm volatile("s_waitcnt vmcnt(0)" ::: "memory");
    __builtin_amdgcn_sched_barrier(0);   // keep consumers below (rule: hipcc
                                         // hoists reg-only ops past asm waits)
}

__device__ inline void consume8(const G8& g, f32x4& A) {
    float2 x;
    x = bf2x2(g.a[0]); A[0] += x.x; A[1] += x.y;
    x = bf2x2(g.a[1]); A[2] += x.x; A[3] += x.y;
    x = bf2x2(g.b[0]); A[0] += x.x; A[1] += x.y;
    x = bf2x2(g.b[1]); A[2] += x.x; A[3] += x.y;
    x = bf2x2(g.c[0]); A[0] += x.x; A[1] += x.y;
    x = bf2x2(g.c[1]); A[2] += x.x; A[3] += x.y;
    x = bf2x2(g.d[0]); A[0] += x.x; A[1] += x.y;
    x = bf2x2(g.d[1]); A[2] += x.x; A[3] += x.y;
    x = bf2x2(g.e[0]); A[0] += x.x; A[1] += x.y;
    x = bf2x2(g.e[1]); A[2] += x.x; A[3] += x.y;
    x = bf2x2(g.f[0]); A[0] += x.x; A[1] += x.y;
    x = bf2x2(g.f[1]); A[2] += x.x; A[3] += x.y;
    x = bf2x2(g.g[0]); A[0] += x.x; A[1] += x.y;
    x = bf2x2(g.g[1]); A[2] += x.x; A[3] += x.y;
    x = bf2x2(g.h[0]); A[0] += x.x; A[1] += x.y;
    x = bf2x2(g.h[1]); A[2] += x.x; A[3] += x.y;
}

#define VOFF(s) ((((unsigned)(s)) << 8) + l8)

// ---- device agg for one node; half-0 lanes return float4 (bias+ReLU applied) ----
// Buckets are sentinel-padded (slot n -> zeroed row): no sanitize, no masking.
// Caller prefetches next node's slots+cnt before this call (overlaps the wait).
__device__ inline float4 agg_node_f(const uint2* __restrict__ hs2,
                                    const unsigned short* __restrict__ cp, int dcnt,
                                    u16x8 sv,
                                    const float* __restrict__ bias,
                                    int node, int half, int l32, unsigned l8) {
    uint2 su = hs2[(size_t)node * 32 + l32];   // self row; same vmcnt window
    G8 g = issue8(hs2, VOFF(sv[0]), VOFF(sv[1]), VOFF(sv[2]), VOFF(sv[3]),
                       VOFF(sv[4]), VOFF(sv[5]), VOFF(sv[6]), VOFF(sv[7]));
    wait_vm0();
    f32x4 A = {0.f, 0.f, 0.f, 0.f};
    consume8(g, A);
    int ch = (min(dcnt, CAP) - half + 1) >> 1;
#pragma unroll 1
    for (int k = 8; k < ch; k += 8) {   // rare tail (deg >= 17), sentinel-padded
        u16x8 x = *(const u16x8*)(cp + k);
        G8 t = issue8(hs2, VOFF(x[0]), VOFF(x[1]), VOFF(x[2]), VOFF(x[3]),
                           VOFF(x[4]), VOFF(x[5]), VOFF(x[6]), VOFF(x[7]));
        wait_vm0();
        consume8(t, A);
    }
    if (half == 0) {   // self term (pre-scaled row)
        float2 v0 = bf2x2(su.x), v1 = bf2x2(su.y);
        A[0] += v0.x; A[1] += v0.y; A[2] += v1.x; A[3] += v1.y;
    }
    float a0 = A[0] + __shfl_xor(A[0], 32);
    float a1 = A[1] + __shfl_xor(A[1], 32);
    float a2 = A[2] + __shfl_xor(A[2], 32);
    float a3 = A[3] + __shfl_xor(A[3], 32);

    float4 o = {0.f, 0.f, 0.f, 0.f};
    if (half == 0) {
        float dn = rsqrtf((float)dcnt + 1.0f);
        float4 b = *(const float4*)&bias[4 * l32];
        o.x = fmaxf(dn * a0 + b.x, 0.0f);
        o.y = fmaxf(dn * a1 + b.y, 0.0f);
        o.z = fmaxf(dn * a2 + b.z, 0.0f);
        o.w = fmaxf(dn * a3 + b.w, 0.0f);
    }
    return o;
}

// ------- FUSED agg1+GEMM2 (1024 thr): phase A — 16 waves aggregate 8 nodes -------
// ------- each into Xs (LDS); phase B — 16-wave MFMA GEMM -> g2b (distinct). -----
__global__ __launch_bounds__(1024) void k_agg_gemm(
        const uint2* __restrict__ hs2, const unsigned short* __restrict__ bucket,
        const int* __restrict__ cnt, const float* __restrict__ bias,
        const unsigned short* __restrict__ Wt, unsigned short* __restrict__ out,
        int n) {
    __shared__ unsigned short Xs[128 * 136];
    __shared__ unsigned short Ws[128 * 136];
    int tid = threadIdx.x;
    int row0 = blockIdx.x * 128;
    int w = tid >> 6;          // 0..15
    int lane = tid & 63;
    int half = lane >> 5;
    int l32 = lane & 31;
    unsigned l8 = (unsigned)l32 * 8u;
    const unsigned short* hb = bucket + half * (CAP / 2);

    // phase A: wave w aggregates nodes row0 + w*8 + j, j=0..7 (slot/cnt pipelined)
    int nb = row0 + w * 8;
    const unsigned short* cp = hb + (size_t)min(nb, n - 1) * CAP;
    u16x8 sv = *(const u16x8*)cp;
    int dcnt = cnt[min(nb, n - 1)];
#pragma unroll 1
    for (int j = 0; j < 8; j++) {
        int node = nb + j;
        // prefetch next node's slots + cnt (issued before the gather wait)
        int nn = min(node + 1, n - 1);
        const unsigned short* cpn = hb + (size_t)nn * CAP;
        u16x8 sv_n = *(const u16x8*)cpn;
        int dc_n = cnt[nn];
        float4 v = {0.f, 0.f, 0.f, 0.f};
        if (node < n)
            v = agg_node_f(hs2, cp, dcnt, sv, bias, node, half, l32, l8);
        if (half == 0) {
            ushort4 o;
            o.x = f2bf(v.x); o.y = f2bf(v.y); o.z = f2bf(v.z); o.w = f2bf(v.w);
            *(ushort4*)&Xs[(w * 8 + j) * 136 + 4 * l32] = o;
        }
        cp = cpn; sv = sv_n; dcnt = dc_n;
    }
    // stage Ws
#pragma unroll
    for (int i = 0; i < 2; i++) {
        int c = tid + 1024 * i;
        int r = c >> 4;
        int kc = (c & 15) * 8;
        uint4 v = *(const uint4*)&Wt[r * D + kc];
        *(uint4*)&Ws[r * 136 + kc] = v;
    }
    __syncthreads();

    // phase B: GEMM on the LDS-resident h1 tile
    gemm_compute16(Xs, Ws, cnt, out, n, row0);
}

// ---- FUSED agg2 + BN-stats (1024 thr, 512 blocks, grid-stride over nodes) ----
__global__ __launch_bounds__(1024) void k_agg_stats(
        const uint2* __restrict__ hs2, const unsigned short* __restrict__ bucket,
        const int* __restrict__ cnt, const float* __restrict__ bias,
        unsigned short* __restrict__ h2, float* __restrict__ S, int N) {
    int tid = threadIdx.x;
    int w = tid >> 6;
    int lane = tid & 63;
    int half = lane >> 5;
    int l32 = lane & 31;
    unsigned l8 = (unsigned)l32 * 8u;
    const unsigned short* hb = bucket + half * (CAP / 2);

    float st0 = 0.f, st1 = 0.f, st2 = 0.f, st3 = 0.f;
    float sq0 = 0.f, sq1 = 0.f, sq2 = 0.f, sq3 = 0.f;

    int stride = gridDim.x * 16;
    int node = blockIdx.x * 16 + w;
    u16x8 sv = {0, 0, 0, 0, 0, 0, 0, 0};
    int dcnt = 0;
    if (node < N) {
        sv = *(const u16x8*)(hb + (size_t)node * CAP);
        dcnt = cnt[node];
    }
#pragma unroll 1
    for (; node < N; node += stride) {
        // prefetch next grid-stride node's slots + cnt (overlaps the wait)
        int nn = min(node + stride, N - 1);
        const unsigned short* cpn = hb + (size_t)nn * CAP;
        u16x8 sv_n = *(const u16x8*)cpn;
        int dc_n = cnt[nn];
        const unsigned short* cp = hb + (size_t)node * CAP;
        float4 v = agg_node_f(hs2, cp, dcnt, sv, bias, node, half, l32, l8);
        if (half == 0) {
            ushort4 o;
            o.x = f2bf(v.x); o.y = f2bf(v.y); o.z = f2bf(v.z); o.w = f2bf(v.w);
            *(ushort4*)&h2[(size_t)node * D + 4 * l32] = o;
            st0 += v.x; st1 += v.y; st2 += v.z; st3 += v.w;
            sq0 += v.x * v.x; sq1 += v.y * v.y;
            sq2 += v.z * v.z; sq3 += v.w * v.w;
        }
        sv = sv_n; dcnt = dc_n;
    }

    __shared__ float sm[16][32][8];
    if (half == 0) {
        sm[w][l32][0] = st0; sm[w][l32][1] = st1;
        sm[w][l32][2] = st2; sm[w][l32][3] = st3;
        sm[w][l32][4] = sq0; sm[w][l32][5] = sq1;
        sm[w][l32][6] = sq2; sm[w][l32][7] = sq3;
    }
    __syncthreads();
    if (tid < D) {
        int f = tid;
        float s = 0.f, q = 0.f;
#pragma unroll
        for (int ww = 0; ww < 16; ww++) {
            s += sm[ww][f >> 2][f & 3];
            q += sm[ww][f >> 2][4 + (f & 3)];
        }
        atomicAdd(&S[f * 16], s);
        atomicAdd(&S[4096 + f * 16], q);
    }
}

// ---------------- BN normalize: bf16 h2 -> f32 out ----------------
__global__ void k_bn(const unsigned* __restrict__ z2, const float* __restrict__ S,
                     const float* __restrict__ gamma, const float* __restrict__ beta,
                     float* __restrict__ out, int N) {
    int i = blockIdx.x * blockDim.x + threadIdx.x;   // uint4 index (8 features)
    int total = N * (D / 8);
    if (i >= total) return;
    int c8 = (i & (D / 8 - 1)) * 8;
    uint4 u = *(const uint4*)&z2[(size_t)i * 4];
    float v[8];
    float2 t;
    t = bf2x2(u.x); v[0] = t.x; v[1] = t.y;
    t = bf2x2(u.y); v[2] = t.x; v[3] = t.y;
    t = bf2x2(u.z); v[4] = t.x; v[5] = t.y;
    t = bf2x2(u.w); v[6] = t.x; v[7] = t.y;
    float invN = 1.0f / (float)N;
    float4 o0, o1;
#pragma unroll
    for (int j = 0; j < 8; j++) {
        float s = S[(c8 + j) * 16];
        float s2 = S[4096 + (c8 + j) * 16];
        float mu = s * invN;
        float iv = rsqrtf(fmaxf(s2 * invN - mu * mu, 0.f) + 1e-5f);
        float val = gamma[c8 + j] * (v[j] - mu) * iv + beta[c8 + j];
        if (j < 4) (&o0.x)[j] = val; else (&o1.x)[j - 4] = val;
    }
    size_t base = (size_t)i * 8;
    *(float4*)&out[base] = o0;
    *(float4*)&out[base + 4] = o1;
}

static inline size_t align_up(size_t x) { return (x + 1023) & ~(size_t)1023; }

extern "C" void kernel_launch(void* const* d_in, const int* in_sizes, int n_in,
                              void* d_out, int out_size, void* d_ws, size_t ws_size,
                              hipStream_t stream) {
    const float* x     = (const float*)d_in[0];
    const int*   ei    = (const int*)d_in[1];
    const float* W1    = (const float*)d_in[2];
    const float* b1    = (const float*)d_in[3];
    const float* W2    = (const float*)d_in[4];
    const float* b2    = (const float*)d_in[5];
    const float* gamma = (const float*)d_in[6];
    const float* beta  = (const float*)d_in[7];

    int N = in_sizes[0] / D;
    int E = in_sizes[1] / 2;
    const int* row = ei;
    const int* col = ei + E;

    char* p = (char*)d_ws;
    int* cnt    = (int*)p;                 // cnt[N] ++ S[8192]: one memset
    float* S    = (float*)(cnt + N);       // strided sums/sumsq, 32KB
    p += align_up((size_t)(N + 8192) * 4);
    unsigned short* bucket = (unsigned short*)p;   // u16 slots, 4.8MB
    p += align_up((size_t)N * CAP * 2);
    // hsb/g2b have N+1 rows: row N is the zeroed sentinel row
    unsigned short* hsb = (unsigned short*)p; p += align_up((size_t)(N + 1) * D * 2);
    unsigned short* g2b = (unsigned short*)p; p += align_up((size_t)(N + 1) * D * 2);
    unsigned short* h2b = (unsigned short*)p; p += align_up((size_t)N * D * 2);
    unsigned short* Wt1 = (unsigned short*)p; p += align_up((size_t)D * D * 2);
    unsigned short* Wt2 = (unsigned short*)p; p += align_up((size_t)D * D * 2);

    int gemmBlocks = (N + 127) / 128;   // 391
    int fillBlocks = (E + 255) / 256;   // 2344

    hipMemsetAsync(cnt, 0, (size_t)(N + 8192) * 4, stream);
    hipMemsetAsync(hsb + (size_t)N * D, 0, (size_t)D * 2, stream);   // sentinel rows
    hipMemsetAsync(g2b + (size_t)N * D, 0, (size_t)D * 2, stream);
    k_histfill<<<fillBlocks, 256, 0, stream>>>(row, col, cnt, bucket, E,
                                               W1, W2, Wt1, Wt2);
    // layer 1 GEMM (+ bucket sentinel pad)
    k_gemm1<<<gemmBlocks, 1024, 0, stream>>>(x, Wt1, cnt, bucket, hsb, N);
    // fused agg1 + layer 2 GEMM: reads hsb, writes g2b (distinct)
    k_agg_gemm<<<gemmBlocks, 1024, 0, stream>>>((const uint2*)hsb, bucket, cnt, b1,
                                                Wt2, g2b, N);
    // fused layer-2 aggregation + BN stats
    k_agg_stats<<<512, 1024, 0, stream>>>((const uint2*)g2b, bucket, cnt, b2,
                                          h2b, S, N);
    // BN normalize
    k_bn<<<(N * (D / 8) + 255) / 256, 256, 0, stream>>>((const unsigned*)h2b, S,
                                                        gamma, beta, (float*)d_out, N);
}

// Round 12
// 226.847 us; speedup vs baseline: 1.3242x; 1.0136x over previous
//
#include <hip/hip_runtime.h>

// GCN block: h1 = ReLU(Agg(x@W1)+b1); h2 = ReLU(Agg(h1@W2)+b2); out = BN(h2)
// R26: revert to verified R24 (229.9us) after R25's fp8 rows failed
// correctness (absmax 2.28 > 0.82 threshold — e4m3's 6% quantization,
// compounded over two layers, needs >=6 mantissa bits; no 1-byte format
// qualifies). Agg passes sit at the established random-64B-line service
// wall (R18 +25%, R20/R21 null, R22/R23 negative, R24 +3%, R25 infeasible).
// One consolidation: sentinel-row zeroing folded into k_histfill's extra
// block (removes 2 graph nodes; tests residual inter-kernel gap cost).

#define D 128
#define CAP 48   // max in-degree capacity; Poisson(12) tail << 48

typedef __attribute__((ext_vector_type(8))) short bf16x8;
typedef __attribute__((ext_vector_type(4))) float f32x4;
typedef __attribute__((ext_vector_type(2))) unsigned u32x2;
typedef __attribute__((ext_vector_type(8))) unsigned short u16x8;

__device__ inline float2 bf2x2(unsigned u) {
    float2 r;
    r.x = __uint_as_float(u << 16);
    r.y = __uint_as_float(u & 0xffff0000u);
    return r;
}
__device__ inline unsigned short f2bf(float f) {
    unsigned u = __float_as_uint(f);
    u += 0x7fffu + ((u >> 16) & 1u);   // round-to-nearest-even
    return (unsigned short)(u >> 16);
}

// ------- fused histogram+fill: one atomic per edge; + W transpose-convert -------
// Split-half u16 bucket: slot s -> half s&1, index s>>1 (contiguous per half).
// Extra block D zeroes the sentinel rows (row N of hsb/g2b).
__global__ void k_histfill(const int* __restrict__ row, const int* __restrict__ col,
                           int* __restrict__ cnt, unsigned short* __restrict__ bucket,
                           int E,
                           const float* __restrict__ W1, const float* __restrict__ W2,
                           unsigned short* __restrict__ Wt1,
                           unsigned short* __restrict__ Wt2,
                           unsigned* __restrict__ hsb_u, unsigned* __restrict__ g2b_u,
                           int N) {
    int e = blockIdx.x * blockDim.x + threadIdx.x;
    if (e < E) {
        int c = col[e];
        int slot = atomicAdd(&cnt[c], 1);
        if (slot < CAP)
            bucket[(size_t)c * CAP + (slot & 1) * (CAP / 2) + (slot >> 1)] =
                (unsigned short)row[e];
    }
    if (blockIdx.x < D) {
        int k = blockIdx.x;
        int t = threadIdx.x;
        if (t < D) Wt1[t * D + k] = f2bf(W1[k * D + t]);
        else       Wt2[(t - D) * D + k] = f2bf(W2[k * D + (t - D)]);
    } else if (blockIdx.x == D) {
        // zero sentinel rows: row N of hsb/g2b = 128 ushorts = 64 uints each
        int t = threadIdx.x;
        size_t base = (size_t)N * (D / 2);   // uint index of row N
        if (t < 64) hsb_u[base + t] = 0u;
        else if (t < 128) g2b_u[base + (t - 64)] = 0u;
    }
}

// ------ 16-wave GEMM compute: wave w -> m-tile w>>1, n-half w&1 (4 n-tiles) ------
__device__ inline void gemm_compute16(const unsigned short* Xs, const unsigned short* Ws,
                                      const int* __restrict__ cnt,
                                      unsigned short* __restrict__ out, int n, int row0) {
    int tid = threadIdx.x;
    int w = tid >> 6;          // 0..15
    int wm = w >> 1;           // m-tile 0..7
    int wn = w & 1;            // n-half 0..1
    int lane = tid & 63;
    int m16 = lane & 15;
    int quad = lane >> 4;

    f32x4 acc[4];
#pragma unroll
    for (int u = 0; u < 4; u++) acc[u] = (f32x4){0.f, 0.f, 0.f, 0.f};

#pragma unroll
    for (int kc = 0; kc < 4; kc++) {
        bf16x8 a = *(const bf16x8*)&Xs[(wm * 16 + m16) * 136 + kc * 32 + quad * 8];
        bf16x8 b[4];
#pragma unroll
        for (int u = 0; u < 4; u++)
            b[u] = *(const bf16x8*)&Ws[((wn * 4 + u) * 16 + m16) * 136 + kc * 32 + quad * 8];
#pragma unroll
        for (int u = 0; u < 4; u++)
            acc[u] = __builtin_amdgcn_mfma_f32_16x16x32_bf16(a, b[u], acc[u], 0, 0, 0);
    }

    int rbase = row0 + wm * 16 + quad * 4;
#pragma unroll
    for (int i = 0; i < 4; i++) {
        int r = rbase + i;
        if (r < n) {
            float sc = rsqrtf((float)cnt[r] + 1.0f);
#pragma unroll
            for (int u = 0; u < 4; u++)
                out[(size_t)r * D + (wn * 4 + u) * 16 + m16] = f2bf(acc[u][i] * sc);
        }
    }
}

// -- GEMM1 (1024 thr, 16 waves): out[r] = bf16((X @ W)[r] * rsqrt(cnt[r]+1)) --
// Also sentinel-pads the bucket (slots [ch, ch+8) per node-half -> n).
__global__ __launch_bounds__(1024) void k_gemm1(
        const float* __restrict__ Xf, const unsigned short* __restrict__ Wt,
        const int* __restrict__ cnt, unsigned short* __restrict__ bucket,
        unsigned short* __restrict__ out, int n) {
    __shared__ unsigned short Xs[128 * 136];   // +8 pad: 2-way banks (free)
    __shared__ unsigned short Ws[128 * 136];
    int tid = threadIdx.x;
    int row0 = blockIdx.x * 128;

#pragma unroll
    for (int i = 0; i < 2; i++) {
        int c = tid + 1024 * i;
        int r = c >> 4;
        int kc = (c & 15) * 8;
        float4 va = {0.f, 0.f, 0.f, 0.f}, vb = {0.f, 0.f, 0.f, 0.f};
        if (row0 + r < n) {
            va = *(const float4*)&Xf[(size_t)(row0 + r) * D + kc];
            vb = *(const float4*)&Xf[(size_t)(row0 + r) * D + kc + 4];
        }
        ushort4 o0, o1;
        o0.x = f2bf(va.x); o0.y = f2bf(va.y); o0.z = f2bf(va.z); o0.w = f2bf(va.w);
        o1.x = f2bf(vb.x); o1.y = f2bf(vb.y); o1.z = f2bf(vb.z); o1.w = f2bf(vb.w);
        *(ushort4*)&Xs[r * 136 + kc] = o0;
        *(ushort4*)&Xs[r * 136 + kc + 4] = o1;
    }
#pragma unroll
    for (int i = 0; i < 2; i++) {
        int c = tid + 1024 * i;
        int r = c >> 4;
        int kc = (c & 15) * 8;
        uint4 v = *(const uint4*)&Wt[r * D + kc];
        *(uint4*)&Ws[r * 136 + kc] = v;
    }
    // sentinel pad: 8 threads per node, 2 writes each (one per half)
    {
        int nl = tid >> 3;
        int t8 = tid & 7;
        int node = row0 + nl;
        if (node < n) {
            int mm = min(cnt[node], CAP);
            unsigned short* bp = bucket + (size_t)node * CAP;
#pragma unroll
            for (int hf = 0; hf < 2; hf++) {
                int j = ((mm - hf + 1) >> 1) + t8;
                if (j < CAP / 2) bp[hf * (CAP / 2) + j] = (unsigned short)n;
            }
        }
    }
    __syncthreads();
    gemm_compute16(Xs, Ws, cnt, out, n, row0);
}

// ---- forced-MLP gather: 8 concurrent row gathers (issue only, no wait) ----
struct G8 { u32x2 a, b, c, d, e, f, g, h; };

__device__ inline G8 issue8(const uint2* __restrict__ hs2,
                            unsigned o0, unsigned o1, unsigned o2, unsigned o3,
                            unsigned o4, unsigned o5, unsigned o6, unsigned o7) {
    G8 r;
    asm volatile(
        "global_load_dwordx2 %0, %8, %16\n\t"
        "global_load_dwordx2 %1, %9, %16\n\t"
        "global_load_dwordx2 %2, %10, %16\n\t"
        "global_load_dwordx2 %3, %11, %16\n\t"
        "global_load_dwordx2 %4, %12, %16\n\t"
        "global_load_dwordx2 %5, %13, %16\n\t"
        "global_load_dwordx2 %6, %14, %16\n\t"
        "global_load_dwordx2 %7, %15, %16"
        : "=&v"(r.a), "=&v"(r.b), "=&v"(r.c), "=&v"(r.d),
          "=&v"(r.e), "=&v"(r.f), "=&v"(r.g), "=&v"(r.h)
        : "v"(o0), "v"(o1), "v"(o2), "v"(o3),
          "v"(o4), "v"(o5), "v"(o6), "v"(o7),
          "s"(hs2));
    return r;
}

__device__ inline void wait_vm0() {
    asm volatile("s_waitcnt vmcnt(0)" ::: "memory");
    __builtin_amdgcn_sched_barrier(0);   // keep consumers below (rule: hipcc
                                         // hoists reg-only ops past asm waits)
}

__device__ inline void consume8(const G8& g, f32x4& A) {
    float2 x;
    x = bf2x2(g.a[0]); A[0] += x.x; A[1] += x.y;
    x = bf2x2(g.a[1]); A[2] += x.x; A[3] += x.y;
    x = bf2x2(g.b[0]); A[0] += x.x; A[1] += x.y;
    x = bf2x2(g.b[1]); A[2] += x.x; A[3] += x.y;
    x = bf2x2(g.c[0]); A[0] += x.x; A[1] += x.y;
    x = bf2x2(g.c[1]); A[2] += x.x; A[3] += x.y;
    x = bf2x2(g.d[0]); A[0] += x.x; A[1] += x.y;
    x = bf2x2(g.d[1]); A[2] += x.x; A[3] += x.y;
    x = bf2x2(g.e[0]); A[0] += x.x; A[1] += x.y;
    x = bf2x2(g.e[1]); A[2] += x.x; A[3] += x.y;
    x = bf2x2(g.f[0]); A[0] += x.x; A[1] += x.y;
    x = bf2x2(g.f[1]); A[2] += x.x; A[3] += x.y;
    x = bf2x2(g.g[0]); A[0] += x.x; A[1] += x.y;
    x = bf2x2(g.g[1]); A[2] += x.x; A[3] += x.y;
    x = bf2x2(g.h[0]); A[0] += x.x; A[1] += x.y;
    x = bf2x2(g.h[1]); A[2] += x.x; A[3] += x.y;
}

#define VOFF(s) ((((unsigned)(s)) << 8) + l8)

// ---- device agg for one node; half-0 lanes return float4 (bias+ReLU applied) ----
// Buckets are sentinel-padded (slot n -> zeroed row): no sanitize, no masking.
// Caller prefetches next node's slots+cnt before this call (overlaps the wait).
__device__ inline float4 agg_node_f(const uint2* __restrict__ hs2,
                                    const unsigned short* __restrict__ cp, int dcnt,
                                    u16x8 sv,
                                    const float* __restrict__ bias,
                                    int node, int half, int l32, unsigned l8) {
    uint2 su = hs2[(size_t)node * 32 + l32];   // self row; same vmcnt window
    G8 g = issue8(hs2, VOFF(sv[0]), VOFF(sv[1]), VOFF(sv[2]), VOFF(sv[3]),
                       VOFF(sv[4]), VOFF(sv[5]), VOFF(sv[6]), VOFF(sv[7]));
    wait_vm0();
    f32x4 A = {0.f, 0.f, 0.f, 0.f};
    consume8(g, A);
    int ch = (min(dcnt, CAP) - half + 1) >> 1;
#pragma unroll 1
    for (int k = 8; k < ch; k += 8) {   // rare tail (deg >= 17), sentinel-padded
        u16x8 x = *(const u16x8*)(cp + k);
        G8 t = issue8(hs2, VOFF(x[0]), VOFF(x[1]), VOFF(x[2]), VOFF(x[3]),
                           VOFF(x[4]), VOFF(x[5]), VOFF(x[6]), VOFF(x[7]));
        wait_vm0();
        consume8(t, A);
    }
    if (half == 0) {   // self term (pre-scaled row)
        float2 v0 = bf2x2(su.x), v1 = bf2x2(su.y);
        A[0] += v0.x; A[1] += v0.y; A[2] += v1.x; A[3] += v1.y;
    }
    float a0 = A[0] + __shfl_xor(A[0], 32);
    float a1 = A[1] + __shfl_xor(A[1], 32);
    float a2 = A[2] + __shfl_xor(A[2], 32);
    float a3 = A[3] + __shfl_xor(A[3], 32);

    float4 o = {0.f, 0.f, 0.f, 0.f};
    if (half == 0) {
        float dn = rsqrtf((float)dcnt + 1.0f);
        float4 b = *(const float4*)&bias[4 * l32];
        o.x = fmaxf(dn * a0 + b.x, 0.0f);
        o.y = fmaxf(dn * a1 + b.y, 0.0f);
        o.z = fmaxf(dn * a2 + b.z, 0.0f);
        o.w = fmaxf(dn * a3 + b.w, 0.0f);
    }
    return o;
}

// ------- FUSED agg1+GEMM2 (1024 thr): phase A — 16 waves aggregate 8 nodes -------
// ------- each into Xs (LDS); phase B — 16-wave MFMA GEMM -> g2b (distinct). -----
__global__ __launch_bounds__(1024) void k_agg_gemm(
        const uint2* __restrict__ hs2, const unsigned short* __restrict__ bucket,
        const int* __restrict__ cnt, const float* __restrict__ bias,
        const unsigned short* __restrict__ Wt, unsigned short* __restrict__ out,
        int n) {
    __shared__ unsigned short Xs[128 * 136];
    __shared__ unsigned short Ws[128 * 136];
    int tid = threadIdx.x;
    int row0 = blockIdx.x * 128;
    int w = tid >> 6;          // 0..15
    int lane = tid & 63;
    int half = lane >> 5;
    int l32 = lane & 31;
    unsigned l8 = (unsigned)l32 * 8u;
    const unsigned short* hb = bucket + half * (CAP / 2);

    // phase A: wave w aggregates nodes row0 + w*8 + j, j=0..7 (slot/cnt pipelined)
    int nb = row0 + w * 8;
    const unsigned short* cp = hb + (size_t)min(nb, n - 1) * CAP;
    u16x8 sv = *(const u16x8*)cp;
    int dcnt = cnt[min(nb, n - 1)];
#pragma unroll 1
    for (int j = 0; j < 8; j++) {
        int node = nb + j;
        // prefetch next node's slots + cnt (issued before the gather wait)
        int nn = min(node + 1, n - 1);
        const unsigned short* cpn = hb + (size_t)nn * CAP;
        u16x8 sv_n = *(const u16x8*)cpn;
        int dc_n = cnt[nn];
        float4 v = {0.f, 0.f, 0.f, 0.f};
        if (node < n)
            v = agg_node_f(hs2, cp, dcnt, sv, bias, node, half, l32, l8);
        if (half == 0) {
            ushort4 o;
            o.x = f2bf(v.x); o.y = f2bf(v.y); o.z = f2bf(v.z); o.w = f2bf(v.w);
            *(ushort4*)&Xs[(w * 8 + j) * 136 + 4 * l32] = o;
        }
        cp = cpn; sv = sv_n; dcnt = dc_n;
    }
    // stage Ws
#pragma unroll
    for (int i = 0; i < 2; i++) {
        int c = tid + 1024 * i;
        int r = c >> 4;
        int kc = (c & 15) * 8;
        uint4 v = *(const uint4*)&Wt[r * D + kc];
        *(uint4*)&Ws[r * 136 + kc] = v;
    }
    __syncthreads();

    // phase B: GEMM on the LDS-resident h1 tile
    gemm_compute16(Xs, Ws, cnt, out, n, row0);
}

// ---- FUSED agg2 + BN-stats (1024 thr, 512 blocks, grid-stride over nodes) ----
__global__ __launch_bounds__(1024) void k_agg_stats(
        const uint2* __restrict__ hs2, const unsigned short* __restrict__ bucket,
        const int* __restrict__ cnt, const float* __restrict__ bias,
        unsigned short* __restrict__ h2, float* __restrict__ S, int N) {
    int tid = threadIdx.x;
    int w = tid >> 6;
    int lane = tid & 63;
    int half = lane >> 5;
    int l32 = lane & 31;
    unsigned l8 = (unsigned)l32 * 8u;
    const unsigned short* hb = bucket + half * (CAP / 2);

    float st0 = 0.f, st1 = 0.f, st2 = 0.f, st3 = 0.f;
    float sq0 = 0.f, sq1 = 0.f, sq2 = 0.f, sq3 = 0.f;

    int stride = gridDim.x * 16;
    int node = blockIdx.x * 16 + w;
    u16x8 sv = {0, 0, 0, 0, 0, 0, 0, 0};
    int dcnt = 0;
    if (node < N) {
        sv = *(const u16x8*)(hb + (size_t)node * CAP);
        dcnt = cnt[node];
    }
#pragma unroll 1
    for (; node < N; node += stride) {
        // prefetch next grid-stride node's slots + cnt (overlaps the wait)
        int nn = min(node + stride, N - 1);
        const unsigned short* cpn = hb + (size_t)nn * CAP;
        u16x8 sv_n = *(const u16x8*)cpn;
        int dc_n = cnt[nn];
        const unsigned short* cp = hb + (size_t)node * CAP;
        float4 v = agg_node_f(hs2, cp, dcnt, sv, bias, node, half, l32, l8);
        if (half == 0) {
            ushort4 o;
            o.x = f2bf(v.x); o.y = f2bf(v.y); o.z = f2bf(v.z); o.w = f2bf(v.w);
            *(ushort4*)&h2[(size_t)node * D + 4 * l32] = o;
            st0 += v.x; st1 += v.y; st2 += v.z; st3 += v.w;
            sq0 += v.x * v.x; sq1 += v.y * v.y;
            sq2 += v.z * v.z; sq3 += v.w * v.w;
        }
        sv = sv_n; dcnt = dc_n;
    }

    __shared__ float sm[16][32][8];
    if (half == 0) {
        sm[w][l32][0] = st0; sm[w][l32][1] = st1;
        sm[w][l32][2] = st2; sm[w][l32][3] = st3;
        sm[w][l32][4] = sq0; sm[w][l32][5] = sq1;
        sm[w][l32][6] = sq2; sm[w][l32][7] = sq3;
    }
    __syncthreads();
    if (tid < D) {
        int f = tid;
        float s = 0.f, q = 0.f;
#pragma unroll
        for (int ww = 0; ww < 16; ww++) {
            s += sm[ww][f >> 2][f & 3];
            q += sm[ww][f >> 2][4 + (f & 3)];
        }
        atomicAdd(&S[f * 16], s);
        atomicAdd(&S[4096 + f * 16], q);
    }
}

// ---------------- BN normalize: bf16 h2 -> f32 out ----------------
__global__ void k_bn(const unsigned* __restrict__ z2, const float* __restrict__ S,
                     const float* __restrict__ gamma, const float* __restrict__ beta,
                     float* __restrict__ out, int N) {
    int i = blockIdx.x * blockDim.x + threadIdx.x;   // uint4 index (8 features)
    int total = N * (D / 8);
    if (i >= total) return;
    int c8 = (i & (D / 8 - 1)) * 8;
    uint4 u = *(const uint4*)&z2[(size_t)i * 4];
    float v[8];
    float2 t;
    t = bf2x2(u.x); v[0] = t.x; v[1] = t.y;
    t = bf2x2(u.y); v[2] = t.x; v[3] = t.y;
    t = bf2x2(u.z); v[4] = t.x; v[5] = t.y;
    t = bf2x2(u.w); v[6] = t.x; v[7] = t.y;
    float invN = 1.0f / (float)N;
    float4 o0, o1;
#pragma unroll
    for (int j = 0; j < 8; j++) {
        float s = S[(c8 + j) * 16];
        float s2 = S[4096 + (c8 + j) * 16];
        float mu = s * invN;
        float iv = rsqrtf(fmaxf(s2 * invN - mu * mu, 0.f) + 1e-5f);
        float val = gamma[c8 + j] * (v[j] - mu) * iv + beta[c8 + j];
        if (j < 4) (&o0.x)[j] = val; else (&o1.x)[j - 4] = val;
    }
    size_t base = (size_t)i * 8;
    *(float4*)&out[base] = o0;
    *(float4*)&out[base + 4] = o1;
}

static inline size_t align_up(size_t x) { return (x + 1023) & ~(size_t)1023; }

extern "C" void kernel_launch(void* const* d_in, const int* in_sizes, int n_in,
                              void* d_out, int out_size, void* d_ws, size_t ws_size,
                              hipStream_t stream) {
    const float* x     = (const float*)d_in[0];
    const int*   ei    = (const int*)d_in[1];
    const float* W1    = (const float*)d_in[2];
    const float* b1    = (const float*)d_in[3];
    const float* W2    = (const float*)d_in[4];
    const float* b2    = (const float*)d_in[5];
    const float* gamma = (const float*)d_in[6];
    const float* beta  = (const float*)d_in[7];

    int N = in_sizes[0] / D;
    int E = in_sizes[1] / 2;
    const int* row = ei;
    const int* col = ei + E;

    char* p = (char*)d_ws;
    int* cnt    = (int*)p;                 // cnt[N] ++ S[8192]: one memset
    float* S    = (float*)(cnt + N);       // strided sums/sumsq, 32KB
    p += align_up((size_t)(N + 8192) * 4);
    unsigned short* bucket = (unsigned short*)p;   // u16 slots, 4.8MB
    p += align_up((size_t)N * CAP * 2);
    // hsb/g2b have N+1 rows: row N is the zeroed sentinel row
    unsigned short* hsb = (unsigned short*)p; p += align_up((size_t)(N + 1) * D * 2);
    unsigned short* g2b = (unsigned short*)p; p += align_up((size_t)(N + 1) * D * 2);
    unsigned short* h2b = (unsigned short*)p; p += align_up((size_t)N * D * 2);
    unsigned short* Wt1 = (unsigned short*)p; p += align_up((size_t)D * D * 2);
    unsigned short* Wt2 = (unsigned short*)p; p += align_up((size_t)D * D * 2);

    int gemmBlocks = (N + 127) / 128;   // 391
    int fillBlocks = (E + 255) / 256;   // 2344 (>= D+1: sentinel-zero block)

    hipMemsetAsync(cnt, 0, (size_t)(N + 8192) * 4, stream);
    k_histfill<<<fillBlocks, 256, 0, stream>>>(row, col, cnt, bucket, E,
                                               W1, W2, Wt1, Wt2,
                                               (unsigned*)hsb, (unsigned*)g2b, N);
    // layer 1 GEMM (+ bucket sentinel pad)
    k_gemm1<<<gemmBlocks, 1024, 0, stream>>>(x, Wt1, cnt, bucket, hsb, N);
    // fused agg1 + layer 2 GEMM: reads hsb, writes g2b (distinct)
    k_agg_gemm<<<gemmBlocks, 1024, 0, stream>>>((const uint2*)hsb, bucket, cnt, b1,
                                                Wt2, g2b, N);
    // fused layer-2 aggregation + BN stats
    k_agg_stats<<<512, 1024, 0, stream>>>((const uint2*)g2b, bucket, cnt, b2,
                                          h2b, S, N);
    // BN normalize
    k_bn<<<(N * (D / 8) + 255) / 256, 256, 0, stream>>>((const unsigned*)h2b, S,
                                                        gamma, beta, (float*)d_out, N);
}